// Round 12
// baseline (203.459 us; speedup 1.0000x reference)
//
#include <hip/hip_runtime.h>

typedef __attribute__((ext_vector_type(8))) short short8;
typedef __attribute__((ext_vector_type(4))) float f32x4;

#define MFMA16(a,b,c) __builtin_amdgcn_mfma_f32_16x16x32_bf16(a,b,c,0,0,0)

__device__ __forceinline__ unsigned short f2bf(float f){
  unsigned int u = __float_as_uint(f);
  u += 0x7FFF + ((u>>16)&1);
  return (unsigned short)(u>>16);
}

__device__ __forceinline__ float fexp2(float x){
#if __has_builtin(__builtin_amdgcn_exp2f)
  return __builtin_amdgcn_exp2f(x);
#else
  return exp2f(x);
#endif
}

__device__ __forceinline__ void gl_lds16(const void* g, void* l){
  __builtin_amdgcn_global_load_lds((const __attribute__((address_space(1))) void*)g,
                                   (__attribute__((address_space(3))) void*)l, 16, 0, 0);
}

__global__ void cvt_bf16(const float* __restrict__ src, unsigned short* __restrict__ dst, int n){
  int i = (blockIdx.x*blockDim.x + threadIdx.x)*4;
  if (i + 3 < n){
    float4 v = *(const float4*)(src + i);
    ushort4 o;
    o.x = f2bf(v.x); o.y = f2bf(v.y); o.z = f2bf(v.z); o.w = f2bf(v.w);
    *(ushort4*)(dst + i) = o;
  }
}

// C[m,n] = sum_k A[m,k]*Bw[n,k]  (Bw row-major [N,K] = W, i.e. y = x W^T)
template<int MODE>
__global__ __launch_bounds__(256) void gemm_bt(
  const unsigned short* __restrict__ A,
  const unsigned short* __restrict__ Bw,
  const float* __restrict__ bias0, const float* __restrict__ bias1, const float* __restrict__ bias2,
  unsigned short* __restrict__ Qo, unsigned short* __restrict__ Ko, unsigned short* __restrict__ VTo,
  float* __restrict__ Co,
  int M, int N, int K)
{
  __shared__ unsigned short As[2][128*32];
  __shared__ unsigned short Bs[2][128*32];
  const int tid = threadIdx.x;
  const int m0 = blockIdx.y*128, n0 = blockIdx.x*128;
  const int w = tid>>6, lane = tid&63, lr = lane&15, lg = lane>>4;
  const int wm = w>>1, wn = w&1;
  const int nk = K/32;

  auto stage = [&](int buf, int kt){
    const unsigned short* Ag = A + (size_t)m0*K + kt*32;
    const unsigned short* Bg = Bw + (size_t)n0*K + kt*32;
    #pragma unroll
    for (int it=0; it<2; ++it){
      int slot = it*256 + tid;
      gl_lds16(Ag + (size_t)(slot>>2)*K + (slot&3)*8, &As[buf][slot*8]);
    }
    #pragma unroll
    for (int it=0; it<2; ++it){
      int slot = it*256 + tid;
      gl_lds16(Bg + (size_t)(slot>>2)*K + (slot&3)*8, &Bs[buf][slot*8]);
    }
  };

  f32x4 acc[4][4] = {};
  stage(0,0);
  for (int kt=0; kt<nk; ++kt){
    int cur = kt&1;
    __syncthreads();
    if (kt+1 < nk) stage(cur^1, kt+1);
    short8 af[4], bfr[4];
    #pragma unroll
    for (int i=0;i<4;++i) af[i]  = *(const short8*)&As[cur][(wm*64 + i*16 + lr)*32 + lg*8];
    #pragma unroll
    for (int j=0;j<4;++j) bfr[j] = *(const short8*)&Bs[cur][(wn*64 + j*16 + lr)*32 + lg*8];
    #pragma unroll
    for (int i=0;i<4;++i)
      #pragma unroll
      for (int j=0;j<4;++j)
        acc[i][j] = MFMA16(af[i], bfr[j], acc[i][j]);
  }

  #pragma unroll
  for (int i=0;i<4;++i){
    #pragma unroll
    for (int j=0;j<4;++j){
      const int n  = n0 + wn*64 + j*16 + lr;
      const int mb = m0 + wm*64 + i*16 + lg*4;
      if (MODE==0){
        const int which = n>>10, nn = n&1023;
        const float bv = (which==0) ? bias0[nn] : (which==1) ? bias1[nn] : bias2[nn];
        const int h = nn>>6, hd = nn&63;
        #pragma unroll
        for (int r=0;r<4;++r){
          const int m = mb + r;
          const int b = m>>11, s = m&2047;
          const unsigned short u = f2bf(acc[i][j][r] + bv);
          const size_t bh = (size_t)(b*16 + h);
          if (which==0)      Qo[(bh*2048 + s)*64 + hd] = u;
          else if (which==1) Ko[(bh*2048 + s)*64 + hd] = u;
          else               VTo[(bh*64 + hd)*2048 + s] = u;
        }
      } else {
        const float bv = bias0[n];
        #pragma unroll
        for (int r=0;r<4;++r){
          const int m = mb + r;
          Co[(size_t)m*N + n] = acc[i][j][r] + bv;
        }
      }
    }
  }
}

// Attention — R9-verified structure (KVBLK=32, Q as A, K as B, static-max exp2
// softmax, P via per-wave LDS, seg-major conflict-free K/V staging).
// R12: 128-thread blocks (2 waves; grid 64 x 32 -> 8 blocks/CU, 16 waves/CU)
// and 1-inst truncating P pack.
// Lane (lr,lg): sacc[t][r] = S[q = q0+lg*4+r][k = k0 + t*16 + lr].
__global__ __launch_bounds__(128, 4) void attn_k(
  const unsigned short* __restrict__ Qb,
  const unsigned short* __restrict__ Kb,
  const unsigned short* __restrict__ VT,
  const float* __restrict__ u_prev,
  unsigned short* __restrict__ Out)  // [B,S,H*HD] bf16
{
  const int qt = blockIdx.x, bh = blockIdx.y;
  const int b = bh>>4, h = bh&15;
  const float lam = 10.f * __expf(-5.f * u_prev[b]);
  const float nlamb = -lam * 1.4426950408889634f;   // -lam * log2(e)
  const int tid = threadIdx.x;
  const int w = tid>>6, lane = tid&63, lr = lane&15, lg = lane>>4;
  const int q0 = qt*32 + w*16;

  const unsigned short* Qp = Qb + (size_t)bh*2048*64;
  const unsigned short* Kp = Kb + (size_t)bh*2048*64;
  const unsigned short* Vp = VT + (size_t)bh*64*2048;

  // Seg-major LDS layouts (16B chunk index c):
  //  K (32 k-rows x 64 d-cols):  c = seg*32 + row, seg in [0,8)
  //  V (64 hd-rows x 32 k-cols): c = seg*64 + row, seg in [0,4)
  __shared__ unsigned short Ks[2][2048];
  __shared__ unsigned short Vs[2][2048];
  __shared__ unsigned short p_lds[2][16][40];   // 80B row stride

  auto stage = [&](int buf, int kt){
    const int k0 = kt*32;
    #pragma unroll
    for (int it=0; it<2; ++it){
      const int c = it*128 + tid;
      gl_lds16(Kp + (size_t)(k0 + (c&31))*64 + (c>>5)*8, &Ks[buf][c*8]);
    }
    #pragma unroll
    for (int it=0; it<2; ++it){
      const int c = it*128 + tid;
      gl_lds16(Vp + (size_t)(c&63)*2048 + k0 + (c>>6)*8, &Vs[buf][c*8]);
    }
  };

  // Q as A-fragment: lane holds Q[q0+lr, lg*8+j (+32)]
  short8 qf0 = *(const short8*)&Qp[(size_t)(q0+lr)*64 +      lg*8];
  short8 qf1 = *(const short8*)&Qp[(size_t)(q0+lr)*64 + 32 + lg*8];

  const float c1 = 0.18033688011112042f;   // log2(e)/8

  float l_run[4] = {0.f, 0.f, 0.f, 0.f};
  f32x4 o0 = {}, o1 = {}, o2 = {}, o3 = {};

  stage(0, 0);
  for (int kt=0; kt<64; ++kt){
    const int cur = kt&1;
    __syncthreads();
    if (kt+1 < 64) stage(cur^1, kt+1);

    const unsigned short* Kc = Ks[cur];
    const unsigned short* Vc = Vs[cur];
    // K frags: element j of (t,s) = K[k0 + t*16 + lr][s*32 + lg*8 + j]
    short8 k00 = *(const short8*)&Kc[(lg*32 +      lr)*8];
    short8 k01 = *(const short8*)&Kc[1024 + (lg*32 +      lr)*8];
    short8 k10 = *(const short8*)&Kc[(lg*32 + 16 + lr)*8];
    short8 k11 = *(const short8*)&Kc[1024 + (lg*32 + 16 + lr)*8];
    // V frags: element j of dt = V[dt*16+lr][k0 + lg*8 + j]
    short8 vf0 = *(const short8*)&Vc[(lg*64 +      lr)*8];
    short8 vf1 = *(const short8*)&Vc[(lg*64 + 16 + lr)*8];
    short8 vf2 = *(const short8*)&Vc[(lg*64 + 32 + lr)*8];
    short8 vf3 = *(const short8*)&Vc[(lg*64 + 48 + lr)*8];

    f32x4 s0 = {}, s1 = {};
    s0 = MFMA16(qf0, k00, s0); s0 = MFMA16(qf1, k01, s0);
    s1 = MFMA16(qf0, k10, s1); s1 = MFMA16(qf1, k11, s1);

    const int k0_ = kt*32;
    const int cls_ = (k0_ > q0 + 117 || k0_ < q0 - 133) ? 2
                   : (k0_ >= q0 - 87 && k0_ <= q0 + 71) ? 0 : 1;
    #pragma unroll
    for (int r=0;r<4;++r){
      const int qi_ = q0 + lg*4 + r;
      float b0 = 0.f, b1 = 0.f;
      if (cls_ == 2){ b0 = nlamb; b1 = nlamb; }
      else if (cls_ == 1){
        int d0 = qi_ - (k0_ + lr);      if (d0<0) d0 = -d0;
        int d1 = qi_ - (k0_ + 16 + lr); if (d1<0) d1 = -d1;
        if (d0 > 102) b0 = nlamb;
        if (d1 > 102) b1 = nlamb;
      }
      const float p0 = fexp2(fmaf(s0[r], c1, b0));
      const float p1 = fexp2(fmaf(s1[r], c1, b1));
      l_run[r] += p0 + p1;
      p_lds[w][lg*4+r][lr]      = (unsigned short)(__float_as_uint(p0)>>16);
      p_lds[w][lg*4+r][16 + lr] = (unsigned short)(__float_as_uint(p1)>>16);
    }
    short8 pa = *(const short8*)&p_lds[w][lr][lg*8];
    o0 = MFMA16(pa, vf0, o0);
    o1 = MFMA16(pa, vf1, o1);
    o2 = MFMA16(pa, vf2, o2);
    o3 = MFMA16(pa, vf3, o3);
  }

  #pragma unroll
  for (int off=1; off<16; off<<=1)
    #pragma unroll
    for (int r=0;r<4;++r)
      l_run[r] += __shfl_xor(l_run[r], off, 64);

  #pragma unroll
  for (int r=0;r<4;++r){
    const int qi = q0 + lg*4 + r;
    const float linv = 1.0f / l_run[r];
    unsigned short* op = &Out[((size_t)b*2048 + qi)*1024 + h*64 + lr];
    op[0]  = f2bf(o0[r] * linv);
    op[16] = f2bf(o1[r] * linv);
    op[32] = f2bf(o2[r] * linv);
    op[48] = f2bf(o3[r] * linv);
  }
}

__global__ void tail_k(const float* __restrict__ u, float* __restrict__ out){
  int i = threadIdx.x;
  if (i < 2) out[4194304 + i] = 10.f*__expf(-5.f*u[i]);
}

extern "C" void kernel_launch(void* const* d_in, const int* in_sizes, int n_in,
                              void* d_out, int out_size, void* d_ws, size_t ws_size,
                              hipStream_t stream){
  const float* x  = (const float*)d_in[0];
  const float* u  = (const float*)d_in[1];
  const float* Wq = (const float*)d_in[2];
  const float* bq = (const float*)d_in[3];
  const float* Wk = (const float*)d_in[4];
  const float* bk = (const float*)d_in[5];
  const float* Wv = (const float*)d_in[6];
  const float* bv = (const float*)d_in[7];
  const float* Wo = (const float*)d_in[8];
  const float* bo = (const float*)d_in[9];
  float* out = (float*)d_out;

  unsigned char* ws = (unsigned char*)d_ws;
  unsigned short* xb    = (unsigned short*)(ws);              // 4096x1024 bf16 (8MB)
  unsigned short* attnb = xb;                                 // reused after GEMM1
  unsigned short* Wqkvb = (unsigned short*)(ws + 8388608);    // 3072x1024 (6MB)
  unsigned short* Wob   = (unsigned short*)(ws + 14680064);   // 1024x1024 (2MB)
  unsigned short* Qb2   = (unsigned short*)(ws + 16777216);   // [B,H,S,HD] (8MB)
  unsigned short* Kb2   = (unsigned short*)(ws + 25165824);   // [B,H,S,HD] (8MB)
  unsigned short* VTb   = (unsigned short*)(ws + 33554432);   // [B,H,HD,S] (8MB)

  cvt_bf16<<<4096, 256, 0, stream>>>(x,  xb, 4194304);
  cvt_bf16<<<1024, 256, 0, stream>>>(Wq, Wqkvb,            1048576);
  cvt_bf16<<<1024, 256, 0, stream>>>(Wk, Wqkvb + 1048576,  1048576);
  cvt_bf16<<<1024, 256, 0, stream>>>(Wv, Wqkvb + 2097152,  1048576);
  cvt_bf16<<<1024, 256, 0, stream>>>(Wo, Wob, 1048576);

  gemm_bt<0><<<dim3(24,32), 256, 0, stream>>>(xb, Wqkvb, bq, bk, bv,
                                              Qb2, Kb2, VTb, nullptr, 4096, 3072, 1024);
  attn_k<<<dim3(64,32), 128, 0, stream>>>(Qb2, Kb2, VTb, u, attnb);
  gemm_bt<1><<<dim3(8,32), 256, 0, stream>>>(attnb, Wob, bo, nullptr, nullptr,
                                             nullptr, nullptr, nullptr, out, 4096, 1024, 1024);
  tail_k<<<1, 64, 0, stream>>>(u, out);
}

// Round 13
// 171.068 us; speedup vs baseline: 1.1893x; 1.1893x over previous
//
#include <hip/hip_runtime.h>

typedef __attribute__((ext_vector_type(8))) short short8;
typedef __attribute__((ext_vector_type(4))) float f32x4;

#define MFMA16(a,b,c) __builtin_amdgcn_mfma_f32_16x16x32_bf16(a,b,c,0,0,0)

__device__ __forceinline__ unsigned short f2bf(float f){
  unsigned int u = __float_as_uint(f);
  u += 0x7FFF + ((u>>16)&1);
  return (unsigned short)(u>>16);
}

__device__ __forceinline__ float fexp2(float x){
#if __has_builtin(__builtin_amdgcn_exp2f)
  return __builtin_amdgcn_exp2f(x);
#else
  return exp2f(x);
#endif
}

__device__ __forceinline__ void gl_lds16(const void* g, void* l){
  __builtin_amdgcn_global_load_lds((const __attribute__((address_space(1))) void*)g,
                                   (__attribute__((address_space(3))) void*)l, 16, 0, 0);
}

__global__ void cvt_bf16(const float* __restrict__ src, unsigned short* __restrict__ dst, int n){
  int i = (blockIdx.x*blockDim.x + threadIdx.x)*4;
  if (i + 3 < n){
    float4 v = *(const float4*)(src + i);
    ushort4 o;
    o.x = f2bf(v.x); o.y = f2bf(v.y); o.z = f2bf(v.z); o.w = f2bf(v.w);
    *(ushort4*)(dst + i) = o;
  }
}

// C[m,n] = sum_k A[m,k]*Bw[n,k]  (Bw row-major [N,K] = W, i.e. y = x W^T)
template<int MODE>
__global__ __launch_bounds__(256) void gemm_bt(
  const unsigned short* __restrict__ A,
  const unsigned short* __restrict__ Bw,
  const float* __restrict__ bias0, const float* __restrict__ bias1, const float* __restrict__ bias2,
  unsigned short* __restrict__ Qo, unsigned short* __restrict__ Ko, unsigned short* __restrict__ VTo,
  float* __restrict__ Co,
  int M, int N, int K)
{
  __shared__ unsigned short As[2][128*32];
  __shared__ unsigned short Bs[2][128*32];
  const int tid = threadIdx.x;
  const int m0 = blockIdx.y*128, n0 = blockIdx.x*128;
  const int w = tid>>6, lane = tid&63, lr = lane&15, lg = lane>>4;
  const int wm = w>>1, wn = w&1;
  const int nk = K/32;

  auto stage = [&](int buf, int kt){
    const unsigned short* Ag = A + (size_t)m0*K + kt*32;
    const unsigned short* Bg = Bw + (size_t)n0*K + kt*32;
    #pragma unroll
    for (int it=0; it<2; ++it){
      int slot = it*256 + tid;
      gl_lds16(Ag + (size_t)(slot>>2)*K + (slot&3)*8, &As[buf][slot*8]);
    }
    #pragma unroll
    for (int it=0; it<2; ++it){
      int slot = it*256 + tid;
      gl_lds16(Bg + (size_t)(slot>>2)*K + (slot&3)*8, &Bs[buf][slot*8]);
    }
  };

  f32x4 acc[4][4] = {};
  stage(0,0);
  for (int kt=0; kt<nk; ++kt){
    int cur = kt&1;
    __syncthreads();
    if (kt+1 < nk) stage(cur^1, kt+1);
    short8 af[4], bfr[4];
    #pragma unroll
    for (int i=0;i<4;++i) af[i]  = *(const short8*)&As[cur][(wm*64 + i*16 + lr)*32 + lg*8];
    #pragma unroll
    for (int j=0;j<4;++j) bfr[j] = *(const short8*)&Bs[cur][(wn*64 + j*16 + lr)*32 + lg*8];
    #pragma unroll
    for (int i=0;i<4;++i)
      #pragma unroll
      for (int j=0;j<4;++j)
        acc[i][j] = MFMA16(af[i], bfr[j], acc[i][j]);
  }

  #pragma unroll
  for (int i=0;i<4;++i){
    #pragma unroll
    for (int j=0;j<4;++j){
      const int n  = n0 + wn*64 + j*16 + lr;
      const int mb = m0 + wm*64 + i*16 + lg*4;
      if (MODE==0){
        const int which = n>>10, nn = n&1023;
        const float bv = (which==0) ? bias0[nn] : (which==1) ? bias1[nn] : bias2[nn];
        const int h = nn>>6, hd = nn&63;
        #pragma unroll
        for (int r=0;r<4;++r){
          const int m = mb + r;
          const int b = m>>11, s = m&2047;
          const unsigned short u = f2bf(acc[i][j][r] + bv);
          const size_t bh = (size_t)(b*16 + h);
          if (which==0)      Qo[(bh*2048 + s)*64 + hd] = u;
          else if (which==1) Ko[(bh*2048 + s)*64 + hd] = u;
          else               VTo[(bh*64 + hd)*2048 + s] = u;
        }
      } else {
        const float bv = bias0[n];
        #pragma unroll
        for (int r=0;r<4;++r){
          const int m = mb + r;
          Co[(size_t)m*N + n] = acc[i][j][r] + bv;
        }
      }
    }
  }
}

// Attention — R9-verified tile body, instantiated twice per wave (dual q-block
// pipeline): block covers 128 q-rows, wave w owns rows q0A=qt*128+w*16 and
// q0B=q0A+64 against one staged K/V tile. Seg-major conflict-free staging,
// static-max exp2 softmax, trunc P pack. grid(16, 32), 256 thr.
// Lane (lr,lg): sacc[t][r] = S[q = q0X+lg*4+r][k = k0 + t*16 + lr].
__global__ __launch_bounds__(256, 2) void attn_k(
  const unsigned short* __restrict__ Qb,
  const unsigned short* __restrict__ Kb,
  const unsigned short* __restrict__ VT,
  const float* __restrict__ u_prev,
  unsigned short* __restrict__ Out)  // [B,S,H*HD] bf16
{
  const int qt = blockIdx.x, bh = blockIdx.y;
  const int b = bh>>4, h = bh&15;
  const float lam = 10.f * __expf(-5.f * u_prev[b]);
  const float nlamb = -lam * 1.4426950408889634f;   // -lam * log2(e)
  const int tid = threadIdx.x;
  const int w = tid>>6, lane = tid&63, lr = lane&15, lg = lane>>4;
  const int q0A = qt*128 + w*16;
  const int q0B = q0A + 64;

  const unsigned short* Qp = Qb + (size_t)bh*2048*64;
  const unsigned short* Kp = Kb + (size_t)bh*2048*64;
  const unsigned short* Vp = VT + (size_t)bh*64*2048;

  // Seg-major LDS layouts (16B chunk index c):
  //  K (32 k-rows x 64 d-cols):  c = seg*32 + row, seg in [0,8)
  //  V (64 hd-rows x 32 k-cols): c = seg*64 + row, seg in [0,4)
  __shared__ unsigned short Ks[2][2048];
  __shared__ unsigned short Vs[2][2048];
  __shared__ unsigned short p_lds[4][2][16][40];   // [wave][half][q][k], 80B rows

  auto stage = [&](int buf, int kt){
    const int k0 = kt*32;
    gl_lds16(Kp + (size_t)(k0 + (tid&31))*64 + (tid>>5)*8, &Ks[buf][tid*8]);
    gl_lds16(Vp + (size_t)(tid&63)*2048 + k0 + (tid>>6)*8, &Vs[buf][tid*8]);
  };

  // Q as A-fragment: lane holds Q[q0X+lr, lg*8+j (+32)]
  short8 qfA0 = *(const short8*)&Qp[(size_t)(q0A+lr)*64 +      lg*8];
  short8 qfA1 = *(const short8*)&Qp[(size_t)(q0A+lr)*64 + 32 + lg*8];
  short8 qfB0 = *(const short8*)&Qp[(size_t)(q0B+lr)*64 +      lg*8];
  short8 qfB1 = *(const short8*)&Qp[(size_t)(q0B+lr)*64 + 32 + lg*8];

  const float c1 = 0.18033688011112042f;   // log2(e)/8

  float lA[4] = {0.f,0.f,0.f,0.f}, lB[4] = {0.f,0.f,0.f,0.f};
  f32x4 oA0 = {}, oA1 = {}, oA2 = {}, oA3 = {};
  f32x4 oB0 = {}, oB1 = {}, oB2 = {}, oB3 = {};

  stage(0, 0);
  for (int kt=0; kt<64; ++kt){
    const int cur = kt&1;
    __syncthreads();
    if (kt+1 < 64) stage(cur^1, kt+1);

    const unsigned short* Kc = Ks[cur];
    const unsigned short* Vc = Vs[cur];
    // K frags: element j of (t,s) = K[k0 + t*16 + lr][s*32 + lg*8 + j]
    short8 k00 = *(const short8*)&Kc[(lg*32 +      lr)*8];
    short8 k01 = *(const short8*)&Kc[1024 + (lg*32 +      lr)*8];
    short8 k10 = *(const short8*)&Kc[(lg*32 + 16 + lr)*8];
    short8 k11 = *(const short8*)&Kc[1024 + (lg*32 + 16 + lr)*8];
    // V frags: element j of dt = V[dt*16+lr][k0 + lg*8 + j]
    short8 vf0 = *(const short8*)&Vc[(lg*64 +      lr)*8];
    short8 vf1 = *(const short8*)&Vc[(lg*64 + 16 + lr)*8];
    short8 vf2 = *(const short8*)&Vc[(lg*64 + 32 + lr)*8];
    short8 vf3 = *(const short8*)&Vc[(lg*64 + 48 + lr)*8];

    const int k0_ = kt*32;

    // ---- half A ----
    {
      f32x4 s0 = {}, s1 = {};
      s0 = MFMA16(qfA0, k00, s0); s0 = MFMA16(qfA1, k01, s0);
      s1 = MFMA16(qfA0, k10, s1); s1 = MFMA16(qfA1, k11, s1);
      const int cls_ = (k0_ > q0A + 117 || k0_ < q0A - 133) ? 2
                     : (k0_ >= q0A - 87 && k0_ <= q0A + 71) ? 0 : 1;
      #pragma unroll
      for (int r=0;r<4;++r){
        const int qi_ = q0A + lg*4 + r;
        float b0 = 0.f, b1 = 0.f;
        if (cls_ == 2){ b0 = nlamb; b1 = nlamb; }
        else if (cls_ == 1){
          int d0 = qi_ - (k0_ + lr);      if (d0<0) d0 = -d0;
          int d1 = qi_ - (k0_ + 16 + lr); if (d1<0) d1 = -d1;
          if (d0 > 102) b0 = nlamb;
          if (d1 > 102) b1 = nlamb;
        }
        const float p0 = fexp2(fmaf(s0[r], c1, b0));
        const float p1 = fexp2(fmaf(s1[r], c1, b1));
        lA[r] += p0 + p1;
        p_lds[w][0][lg*4+r][lr]      = (unsigned short)(__float_as_uint(p0)>>16);
        p_lds[w][0][lg*4+r][16 + lr] = (unsigned short)(__float_as_uint(p1)>>16);
      }
      short8 pa = *(const short8*)&p_lds[w][0][lr][lg*8];
      oA0 = MFMA16(pa, vf0, oA0);
      oA1 = MFMA16(pa, vf1, oA1);
      oA2 = MFMA16(pa, vf2, oA2);
      oA3 = MFMA16(pa, vf3, oA3);
    }
    // ---- half B ----
    {
      f32x4 s0 = {}, s1 = {};
      s0 = MFMA16(qfB0, k00, s0); s0 = MFMA16(qfB1, k01, s0);
      s1 = MFMA16(qfB0, k10, s1); s1 = MFMA16(qfB1, k11, s1);
      const int cls_ = (k0_ > q0B + 117 || k0_ < q0B - 133) ? 2
                     : (k0_ >= q0B - 87 && k0_ <= q0B + 71) ? 0 : 1;
      #pragma unroll
      for (int r=0;r<4;++r){
        const int qi_ = q0B + lg*4 + r;
        float b0 = 0.f, b1 = 0.f;
        if (cls_ == 2){ b0 = nlamb; b1 = nlamb; }
        else if (cls_ == 1){
          int d0 = qi_ - (k0_ + lr);      if (d0<0) d0 = -d0;
          int d1 = qi_ - (k0_ + 16 + lr); if (d1<0) d1 = -d1;
          if (d0 > 102) b0 = nlamb;
          if (d1 > 102) b1 = nlamb;
        }
        const float p0 = fexp2(fmaf(s0[r], c1, b0));
        const float p1 = fexp2(fmaf(s1[r], c1, b1));
        lB[r] += p0 + p1;
        p_lds[w][1][lg*4+r][lr]      = (unsigned short)(__float_as_uint(p0)>>16);
        p_lds[w][1][lg*4+r][16 + lr] = (unsigned short)(__float_as_uint(p1)>>16);
      }
      short8 pa = *(const short8*)&p_lds[w][1][lr][lg*8];
      oB0 = MFMA16(pa, vf0, oB0);
      oB1 = MFMA16(pa, vf1, oB1);
      oB2 = MFMA16(pa, vf2, oB2);
      oB3 = MFMA16(pa, vf3, oB3);
    }
  }

  #pragma unroll
  for (int off=1; off<16; off<<=1)
    #pragma unroll
    for (int r=0;r<4;++r){
      lA[r] += __shfl_xor(lA[r], off, 64);
      lB[r] += __shfl_xor(lB[r], off, 64);
    }

  #pragma unroll
  for (int r=0;r<4;++r){
    const int qiA = q0A + lg*4 + r;
    const float liA = 1.0f / lA[r];
    unsigned short* opA = &Out[((size_t)b*2048 + qiA)*1024 + h*64 + lr];
    opA[0]  = f2bf(oA0[r] * liA);
    opA[16] = f2bf(oA1[r] * liA);
    opA[32] = f2bf(oA2[r] * liA);
    opA[48] = f2bf(oA3[r] * liA);
    const int qiB = q0B + lg*4 + r;
    const float liB = 1.0f / lB[r];
    unsigned short* opB = &Out[((size_t)b*2048 + qiB)*1024 + h*64 + lr];
    opB[0]  = f2bf(oB0[r] * liB);
    opB[16] = f2bf(oB1[r] * liB);
    opB[32] = f2bf(oB2[r] * liB);
    opB[48] = f2bf(oB3[r] * liB);
  }
}

__global__ void tail_k(const float* __restrict__ u, float* __restrict__ out){
  int i = threadIdx.x;
  if (i < 2) out[4194304 + i] = 10.f*__expf(-5.f*u[i]);
}

extern "C" void kernel_launch(void* const* d_in, const int* in_sizes, int n_in,
                              void* d_out, int out_size, void* d_ws, size_t ws_size,
                              hipStream_t stream){
  const float* x  = (const float*)d_in[0];
  const float* u  = (const float*)d_in[1];
  const float* Wq = (const float*)d_in[2];
  const float* bq = (const float*)d_in[3];
  const float* Wk = (const float*)d_in[4];
  const float* bk = (const float*)d_in[5];
  const float* Wv = (const float*)d_in[6];
  const float* bv = (const float*)d_in[7];
  const float* Wo = (const float*)d_in[8];
  const float* bo = (const float*)d_in[9];
  float* out = (float*)d_out;

  unsigned char* ws = (unsigned char*)d_ws;
  unsigned short* xb    = (unsigned short*)(ws);              // 4096x1024 bf16 (8MB)
  unsigned short* attnb = xb;                                 // reused after GEMM1
  unsigned short* Wqkvb = (unsigned short*)(ws + 8388608);    // 3072x1024 (6MB)
  unsigned short* Wob   = (unsigned short*)(ws + 14680064);   // 1024x1024 (2MB)
  unsigned short* Qb2   = (unsigned short*)(ws + 16777216);   // [B,H,S,HD] (8MB)
  unsigned short* Kb2   = (unsigned short*)(ws + 25165824);   // [B,H,S,HD] (8MB)
  unsigned short* VTb   = (unsigned short*)(ws + 33554432);   // [B,H,HD,S] (8MB)

  cvt_bf16<<<4096, 256, 0, stream>>>(x,  xb, 4194304);
  cvt_bf16<<<1024, 256, 0, stream>>>(Wq, Wqkvb,            1048576);
  cvt_bf16<<<1024, 256, 0, stream>>>(Wk, Wqkvb + 1048576,  1048576);
  cvt_bf16<<<1024, 256, 0, stream>>>(Wv, Wqkvb + 2097152,  1048576);
  cvt_bf16<<<1024, 256, 0, stream>>>(Wo, Wob, 1048576);

  gemm_bt<0><<<dim3(24,32), 256, 0, stream>>>(xb, Wqkvb, bq, bk, bv,
                                              Qb2, Kb2, VTb, nullptr, 4096, 3072, 1024);
  attn_k<<<dim3(16,32), 256, 0, stream>>>(Qb2, Kb2, VTb, u, attnb);
  gemm_bt<1><<<dim3(8,32), 256, 0, stream>>>(attnb, Wob, bo, nullptr, nullptr,
                                             nullptr, nullptr, nullptr, out, 4096, 1024, 1024);
  tail_k<<<1, 64, 0, stream>>>(u, out);
}

// Round 14
// 152.526 us; speedup vs baseline: 1.3339x; 1.1216x over previous
//
#include <hip/hip_runtime.h>

typedef __attribute__((ext_vector_type(8))) short short8;
typedef __attribute__((ext_vector_type(4))) float f32x4;

#define MFMA16(a,b,c) __builtin_amdgcn_mfma_f32_16x16x32_bf16(a,b,c,0,0,0)

__device__ __forceinline__ unsigned short f2bf(float f){
  unsigned int u = __float_as_uint(f);
  u += 0x7FFF + ((u>>16)&1);
  return (unsigned short)(u>>16);
}

__device__ __forceinline__ float fexp2(float x){
#if __has_builtin(__builtin_amdgcn_exp2f)
  return __builtin_amdgcn_exp2f(x);
#else
  return exp2f(x);
#endif
}

__device__ __forceinline__ void gl_lds16(const void* g, void* l){
  __builtin_amdgcn_global_load_lds((const __attribute__((address_space(1))) void*)g,
                                   (__attribute__((address_space(3))) void*)l, 16, 0, 0);
}

__global__ void cvt_bf16(const float* __restrict__ src, unsigned short* __restrict__ dst, int n){
  int i = (blockIdx.x*blockDim.x + threadIdx.x)*4;
  if (i + 3 < n){
    float4 v = *(const float4*)(src + i);
    ushort4 o;
    o.x = f2bf(v.x); o.y = f2bf(v.y); o.z = f2bf(v.z); o.w = f2bf(v.w);
    *(ushort4*)(dst + i) = o;
  }
}

// C[m,n] = sum_k A[m,k]*Bw[n,k]  (Bw row-major [N,K] = W, i.e. y = x W^T)
template<int MODE>
__global__ __launch_bounds__(256) void gemm_bt(
  const unsigned short* __restrict__ A,
  const unsigned short* __restrict__ Bw,
  const float* __restrict__ bias0, const float* __restrict__ bias1, const float* __restrict__ bias2,
  unsigned short* __restrict__ Qo, unsigned short* __restrict__ Ko, unsigned short* __restrict__ VTo,
  float* __restrict__ Co,
  int M, int N, int K)
{
  __shared__ unsigned short As[2][128*32];
  __shared__ unsigned short Bs[2][128*32];
  const int tid = threadIdx.x;
  const int m0 = blockIdx.y*128, n0 = blockIdx.x*128;
  const int w = tid>>6, lane = tid&63, lr = lane&15, lg = lane>>4;
  const int wm = w>>1, wn = w&1;
  const int nk = K/32;

  auto stage = [&](int buf, int kt){
    const unsigned short* Ag = A + (size_t)m0*K + kt*32;
    const unsigned short* Bg = Bw + (size_t)n0*K + kt*32;
    #pragma unroll
    for (int it=0; it<2; ++it){
      int slot = it*256 + tid;
      gl_lds16(Ag + (size_t)(slot>>2)*K + (slot&3)*8, &As[buf][slot*8]);
    }
    #pragma unroll
    for (int it=0; it<2; ++it){
      int slot = it*256 + tid;
      gl_lds16(Bg + (size_t)(slot>>2)*K + (slot&3)*8, &Bs[buf][slot*8]);
    }
  };

  f32x4 acc[4][4] = {};
  stage(0,0);
  for (int kt=0; kt<nk; ++kt){
    int cur = kt&1;
    __syncthreads();
    if (kt+1 < nk) stage(cur^1, kt+1);
    short8 af[4], bfr[4];
    #pragma unroll
    for (int i=0;i<4;++i) af[i]  = *(const short8*)&As[cur][(wm*64 + i*16 + lr)*32 + lg*8];
    #pragma unroll
    for (int j=0;j<4;++j) bfr[j] = *(const short8*)&Bs[cur][(wn*64 + j*16 + lr)*32 + lg*8];
    #pragma unroll
    for (int i=0;i<4;++i)
      #pragma unroll
      for (int j=0;j<4;++j)
        acc[i][j] = MFMA16(af[i], bfr[j], acc[i][j]);
  }

  #pragma unroll
  for (int i=0;i<4;++i){
    #pragma unroll
    for (int j=0;j<4;++j){
      const int n  = n0 + wn*64 + j*16 + lr;
      const int mb = m0 + wm*64 + i*16 + lg*4;
      if (MODE==0){
        const int which = n>>10, nn = n&1023;
        const float bv = (which==0) ? bias0[nn] : (which==1) ? bias1[nn] : bias2[nn];
        const int h = nn>>6, hd = nn&63;
        #pragma unroll
        for (int r=0;r<4;++r){
          const int m = mb + r;
          const int b = m>>11, s = m&2047;
          const unsigned short u = f2bf(acc[i][j][r] + bv);
          const size_t bh = (size_t)(b*16 + h);
          if (which==0)      Qo[(bh*2048 + s)*64 + hd] = u;
          else if (which==1) Ko[(bh*2048 + s)*64 + hd] = u;
          else               VTo[(bh*64 + hd)*2048 + s] = u;
        }
      } else {
        const float bv = bias0[n];
        #pragma unroll
        for (int r=0;r<4;++r){
          const int m = mb + r;
          Co[(size_t)m*N + n] = acc[i][j][r] + bv;
        }
      }
    }
  }
}

// Attention — R9-verified dataflow (KVBLK=32, 4 waves, seg-major staging,
// static-max exp2 softmax, trunc P pack), software-pipelined one tile ahead:
// iteration kt finishes tile kt (softmax+PV) and computes QK for tile kt+1.
// grid(32, 32), 256 thr. Lane (lr,lg): s{0,1}[r] = S[q0+lg*4+r][k0+t*16+lr].
__global__ __launch_bounds__(256, 4) void attn_k(
  const unsigned short* __restrict__ Qb,
  const unsigned short* __restrict__ Kb,
  const unsigned short* __restrict__ VT,
  const float* __restrict__ u_prev,
  unsigned short* __restrict__ Out)  // [B,S,H*HD] bf16
{
  const int qt = blockIdx.x, bh = blockIdx.y;
  const int b = bh>>4, h = bh&15;
  const float lam = 10.f * __expf(-5.f * u_prev[b]);
  const float nlamb = -lam * 1.4426950408889634f;   // -lam * log2(e)
  const int tid = threadIdx.x;
  const int w = tid>>6, lane = tid&63, lr = lane&15, lg = lane>>4;
  const int q0 = qt*64 + w*16;

  const unsigned short* Qp = Qb + (size_t)bh*2048*64;
  const unsigned short* Kp = Kb + (size_t)bh*2048*64;
  const unsigned short* Vp = VT + (size_t)bh*64*2048;

  // Seg-major LDS layouts (16B chunk index c):
  //  K (32 k-rows x 64 d-cols):  c = seg*32 + row, seg in [0,8)
  //  V (64 hd-rows x 32 k-cols): c = seg*64 + row, seg in [0,4)
  __shared__ unsigned short Ks[2][2048];
  __shared__ unsigned short Vs[2][2048];
  __shared__ unsigned short p_lds[4][16][40];   // 80B row stride

  auto stage = [&](int buf, int kt){
    const int k0 = kt*32;
    gl_lds16(Kp + (size_t)(k0 + (tid&31))*64 + (tid>>5)*8, &Ks[buf][tid*8]);
    gl_lds16(Vp + (size_t)(tid&63)*2048 + k0 + (tid>>6)*8, &Vs[buf][tid*8]);
  };

  // Q as A-fragment: lane holds Q[q0+lr, lg*8+j (+32)]
  short8 qf0 = *(const short8*)&Qp[(size_t)(q0+lr)*64 +      lg*8];
  short8 qf1 = *(const short8*)&Qp[(size_t)(q0+lr)*64 + 32 + lg*8];

  const float c1 = 0.18033688011112042f;   // log2(e)/8

  float l_run[4] = {0.f, 0.f, 0.f, 0.f};
  f32x4 o0 = {}, o1 = {}, o2 = {}, o3 = {};

  // prologue: stage tiles 0 and 1; compute scores for tile 0
  stage(0, 0);
  __syncthreads();
  stage(1, 1);
  f32x4 s0 = {}, s1 = {};
  {
    const unsigned short* Kc = Ks[0];
    short8 k00 = *(const short8*)&Kc[(lg*32 +      lr)*8];
    short8 k01 = *(const short8*)&Kc[1024 + (lg*32 +      lr)*8];
    short8 k10 = *(const short8*)&Kc[(lg*32 + 16 + lr)*8];
    short8 k11 = *(const short8*)&Kc[1024 + (lg*32 + 16 + lr)*8];
    s0 = MFMA16(qf0, k00, s0); s0 = MFMA16(qf1, k01, s0);
    s1 = MFMA16(qf0, k10, s1); s1 = MFMA16(qf1, k11, s1);
  }

  for (int kt=0; kt<64; ++kt){
    const int cur = kt&1;
    const int k0_ = kt*32;

    // --- finish tile kt: softmax on s0/s1 -> P ---
    const int cls_ = (k0_ > q0 + 117 || k0_ < q0 - 133) ? 2
                   : (k0_ >= q0 - 87 && k0_ <= q0 + 71) ? 0 : 1;
    #pragma unroll
    for (int r=0;r<4;++r){
      const int qi_ = q0 + lg*4 + r;
      float b0 = 0.f, b1 = 0.f;
      if (cls_ == 2){ b0 = nlamb; b1 = nlamb; }
      else if (cls_ == 1){
        int d0 = qi_ - (k0_ + lr);      if (d0<0) d0 = -d0;
        int d1 = qi_ - (k0_ + 16 + lr); if (d1<0) d1 = -d1;
        if (d0 > 102) b0 = nlamb;
        if (d1 > 102) b1 = nlamb;
      }
      const float p0 = fexp2(fmaf(s0[r], c1, b0));
      const float p1 = fexp2(fmaf(s1[r], c1, b1));
      l_run[r] += p0 + p1;
      p_lds[w][lg*4+r][lr]      = (unsigned short)(__float_as_uint(p0)>>16);
      p_lds[w][lg*4+r][16 + lr] = (unsigned short)(__float_as_uint(p1)>>16);
    }

    // --- buffer-cur reads for tile kt (before barrier / next stage) ---
    const unsigned short* Vc = Vs[cur];
    short8 vf0 = *(const short8*)&Vc[(lg*64 +      lr)*8];
    short8 vf1 = *(const short8*)&Vc[(lg*64 + 16 + lr)*8];
    short8 vf2 = *(const short8*)&Vc[(lg*64 + 32 + lr)*8];
    short8 vf3 = *(const short8*)&Vc[(lg*64 + 48 + lr)*8];
    short8 pa = *(const short8*)&p_lds[w][lr][lg*8];

    __syncthreads();                    // stage(kt+1) complete; buf-cur reads drained
    if (kt+2 < 64) stage(cur, kt+2);    // overwrite buf cur (safe post-barrier)

    // --- scores for tile kt+1 (overlaps PV below via ILP) ---
    f32x4 sn0 = {}, sn1 = {};
    if (kt+1 < 64){
      const unsigned short* Kc = Ks[cur^1];
      short8 k00 = *(const short8*)&Kc[(lg*32 +      lr)*8];
      short8 k01 = *(const short8*)&Kc[1024 + (lg*32 +      lr)*8];
      short8 k10 = *(const short8*)&Kc[(lg*32 + 16 + lr)*8];
      short8 k11 = *(const short8*)&Kc[1024 + (lg*32 + 16 + lr)*8];
      sn0 = MFMA16(qf0, k00, sn0); sn0 = MFMA16(qf1, k01, sn0);
      sn1 = MFMA16(qf0, k10, sn1); sn1 = MFMA16(qf1, k11, sn1);
    }

    // --- PV for tile kt ---
    o0 = MFMA16(pa, vf0, o0);
    o1 = MFMA16(pa, vf1, o1);
    o2 = MFMA16(pa, vf2, o2);
    o3 = MFMA16(pa, vf3, o3);

    s0 = sn0; s1 = sn1;
  }

  #pragma unroll
  for (int off=1; off<16; off<<=1)
    #pragma unroll
    for (int r=0;r<4;++r)
      l_run[r] += __shfl_xor(l_run[r], off, 64);

  #pragma unroll
  for (int r=0;r<4;++r){
    const int qi = q0 + lg*4 + r;
    const float linv = 1.0f / l_run[r];
    unsigned short* op = &Out[((size_t)b*2048 + qi)*1024 + h*64 + lr];
    op[0]  = f2bf(o0[r] * linv);
    op[16] = f2bf(o1[r] * linv);
    op[32] = f2bf(o2[r] * linv);
    op[48] = f2bf(o3[r] * linv);
  }
}

__global__ void tail_k(const float* __restrict__ u, float* __restrict__ out){
  int i = threadIdx.x;
  if (i < 2) out[4194304 + i] = 10.f*__expf(-5.f*u[i]);
}

extern "C" void kernel_launch(void* const* d_in, const int* in_sizes, int n_in,
                              void* d_out, int out_size, void* d_ws, size_t ws_size,
                              hipStream_t stream){
  const float* x  = (const float*)d_in[0];
  const float* u  = (const float*)d_in[1];
  const float* Wq = (const float*)d_in[2];
  const float* bq = (const float*)d_in[3];
  const float* Wk = (const float*)d_in[4];
  const float* bk = (const float*)d_in[5];
  const float* Wv = (const float*)d_in[6];
  const float* bv = (const float*)d_in[7];
  const float* Wo = (const float*)d_in[8];
  const float* bo = (const float*)d_in[9];
  float* out = (float*)d_out;

  unsigned char* ws = (unsigned char*)d_ws;
  unsigned short* xb    = (unsigned short*)(ws);              // 4096x1024 bf16 (8MB)
  unsigned short* attnb = xb;                                 // reused after GEMM1
  unsigned short* Wqkvb = (unsigned short*)(ws + 8388608);    // 3072x1024 (6MB)
  unsigned short* Wob   = (unsigned short*)(ws + 14680064);   // 1024x1024 (2MB)
  unsigned short* Qb2   = (unsigned short*)(ws + 16777216);   // [B,H,S,HD] (8MB)
  unsigned short* Kb2   = (unsigned short*)(ws + 25165824);   // [B,H,S,HD] (8MB)
  unsigned short* VTb   = (unsigned short*)(ws + 33554432);   // [B,H,HD,S] (8MB)

  cvt_bf16<<<4096, 256, 0, stream>>>(x,  xb, 4194304);
  cvt_bf16<<<1024, 256, 0, stream>>>(Wq, Wqkvb,            1048576);
  cvt_bf16<<<1024, 256, 0, stream>>>(Wk, Wqkvb + 1048576,  1048576);
  cvt_bf16<<<1024, 256, 0, stream>>>(Wv, Wqkvb + 2097152,  1048576);
  cvt_bf16<<<1024, 256, 0, stream>>>(Wo, Wob, 1048576);

  gemm_bt<0><<<dim3(24,32), 256, 0, stream>>>(xb, Wqkvb, bq, bk, bv,
                                              Qb2, Kb2, VTb, nullptr, 4096, 3072, 1024);
  attn_k<<<dim3(32,32), 256, 0, stream>>>(Qb2, Kb2, VTb, u, attnb);
  gemm_bt<1><<<dim3(8,32), 256, 0, stream>>>(attnb, Wob, bo, nullptr, nullptr,
                                             nullptr, nullptr, nullptr, out, 4096, 1024, 1024);
  tail_k<<<1, 64, 0, stream>>>(u, out);
}